// Round 15
// baseline (993.299 us; speedup 1.0000x reference)
//
#include <hip/hip_runtime.h>
#include <math.h>

// VQ quantizer: z [65536, 256] fp32, codebook [1024, 256] fp32.
// Outputs flat: z_q [16777216] | loss [1] | indices [65536] (as float values).
//
// Numerics contract (validated R1..R14, absmax 0.0 — keep bit-identical):
//   A_t = sum(z_t^2)  -- numpy pairwise order (8-acc chains, 128-blocks, fixed tree)
//   B_n = sum(e_n^2)  -- same
//   d   = fl( fl(A+B) - 2*M ),  M = fp32 fma-accumulated dot, k ascending
//   argmin: global first-min == lexicographic min of key (d_bits<<32 | idx)
//   z_q_out = fl( z + fl(e - z) ),  loss = fl(mf + fl(10*mf)), mf=(float)(Σdx²/2^24)
//
// R14 lesson: LDS return BW is per-INSTRUCTION (~12cyc/b128, 1024B to VGPRs,
// broadcast or not). 8x8 tile with both operands in LDS = 16 b128/4k = 1.5x
// VALU time. R15: z in LDS (8 b128/4k, XOR-swizzled) + e DIRECT FROM GLOBAL
// (codebook L2-resident, 16KB chunk L1-reused across ks) -> LDS pipe 0.75x
// VALU, VMEM off the critical path, VALU finally the binding pipe.
// HARD RULE: never pass a 2nd __launch_bounds__ arg (VGPR=64 pin + GB spills).

#define NTOK     65536
#define DDIM     256
#define NCODE    1024
#define LOSS_OFF 16777216
#define IDX_OFF  16777217

// ws layout: [0] double loss_acc | [64] float wsB[1024] | [8192] u64 keys[65536]
//            | [532480] float wsA[65536]

#define GLOAD_LDS16(gp, lp)                                                       \
    __builtin_amdgcn_global_load_lds(                                             \
        (const __attribute__((address_space(1))) void*)(gp),                      \
        (__attribute__((address_space(3))) void*)(lp), 16, 0, 0)

// ---------------- kernel 0: B_n (numpy-pairwise), zero loss, init argmin keys.
__global__ void vq_prep(const float* __restrict__ cb, float* __restrict__ wsB,
                        double* __restrict__ loss_acc,
                        unsigned long long* __restrict__ keys)
{
#pragma clang fp contract(off)
    int gid = blockIdx.x * blockDim.x + threadIdx.x;
    if (gid == 0) *loss_acc = 0.0;
    unsigned long long* kp = keys + (size_t)gid * 4;
    kp[0] = kp[1] = kp[2] = kp[3] = 0xFFFFFFFFFFFFFFFFull;
    if (gid >= NCODE) return;
    const float* a = cb + gid * DDIM;
    float half[2];
    for (int h = 0; h < 2; ++h) {
        const float* b = a + h * 128;
        float r[8];
#pragma unroll
        for (int j = 0; j < 8; ++j) { float v = b[j]; r[j] = v * v; }
        for (int i = 8; i < 128; i += 8) {
#pragma unroll
            for (int j = 0; j < 8; ++j) { float v = b[i + j]; float s = v * v; r[j] = r[j] + s; }
        }
        half[h] = ((r[0] + r[1]) + (r[2] + r[3])) + ((r[4] + r[5]) + (r[6] + r[7]));
    }
    wsB[gid] = half[0] + half[1];
}

// ---------------- kernel 0b: A_t (numpy-pairwise) for every token.
__global__ void vq_anorm(const float* __restrict__ z, float* __restrict__ wsA)
{
#pragma clang fp contract(off)
    int t = blockIdx.x * blockDim.x + threadIdx.x;
    const float* a = z + (size_t)t * DDIM;
    float half[2];
    for (int h = 0; h < 2; ++h) {
        const float* b = a + h * 128;
        float r[8];
#pragma unroll
        for (int j = 0; j < 8; ++j) { float v = b[j]; r[j] = v * v; }
        for (int i = 8; i < 128; i += 8) {
#pragma unroll
            for (int j = 0; j < 8; ++j) { float v = b[i + j]; float s = v * v; r[j] = r[j] + s; }
        }
        half[h] = ((r[0] + r[1]) + (r[2] + r[3])) + ((r[4] + r[5]) + (r[6] + r[7]));
    }
    wsA[t] = half[0] + half[1];
}

// ---------------- kernel 1: distance GEMM + per-tile argmin -> atomicMin keys.
// Grid 4096 x 256: block b -> xcd = b&7, sl = b>>3, token-tile tt = xcd*64+(sl>>3),
// code-tile ct = sl&7 (siblings of a token-tile share one XCD's L2; codebook
// is fully L2-resident at 1 MB).
// Thread (tx,ty): tokens {4ty+i, 64+4ty+i} from LDS zs [token][32k] (f4-blocks
// XOR-swizzled, gload_lds-staged), codes {4tx+j, 64+4tx+j} straight from global.
__global__ __launch_bounds__(256) void vq_main(const float* __restrict__ z,
                                               const float* __restrict__ cb,
                                               const float* __restrict__ wsB,
                                               const float* __restrict__ wsA,
                                               unsigned long long* __restrict__ keys)
{
    __shared__ float zs[128 * 32];   // 16 KB, [token][32k], f4-col p holds ks p^(row&7)
    __shared__ float Bl[128];

    const int tid = threadIdx.x;
    const int tx = tid & 15, ty = tid >> 4;      // 16x16 thread grid
    const int b = blockIdx.x;
    const int xcd = b & 7, sl = b >> 3;
    const int tt = xcd * 64 + (sl >> 3);
    const int ct = sl & 7;
    const int t0 = tt * 128;
    const int n0 = ct * 128;

    if (tid < 128) Bl[tid] = wsB[n0 + tid];

    // z staging: 4 slots/thread, fr = tid+256s -> row fr>>3, phys f4 col fr&7;
    // source supplies logical col (fr&7)^(row&7)  (both-sides swizzle, rule 21)
    const char* zc = (const char*)z;
    long zoff[4];
#pragma unroll
    for (int s = 0; s < 4; ++s) {
        int fr = tid + 256 * s;
        int row = fr >> 3;
        int csrc = (fr & 7) ^ (row & 7);
        zoff[s] = (long)(t0 + row) * 1024 + csrc * 16;
    }

    // e base pointers (codes 4tx+j and 64+4tx+j), bumped by 128 B per kc;
    // per-load offset j*1024 + ks*16 <= 3184 B fits the 13-bit signed imm.
    const char* eb0 = (const char*)(cb + (size_t)(n0 + 4 * tx) * DDIM);
    const char* eb1 = (const char*)(cb + (size_t)(n0 + 64 + 4 * tx) * DDIM);

    float acc[8][8];
#pragma unroll
    for (int i = 0; i < 8; ++i)
#pragma unroll
        for (int j = 0; j < 8; ++j) acc[i][j] = 0.0f;

    const int rsw = (4 * ty) & 7;    // (4ty+i)&7 = rsw^? no: varies with i; compute per i below

    for (int kc = 0; kc < 8; ++kc) {
        if (kc) __syncthreads();             // readers of kc-1 done
#pragma unroll
        for (int s = 0; s < 4; ++s)
            GLOAD_LDS16(zc + (zoff[s] + kc * 128), (char*)zs + (tid + 256 * s) * 16);
        __syncthreads();                     // vmcnt(0) drain + visibility

#pragma unroll
        for (int ks = 0; ks < 8; ++ks) {
            // 8 z b128: rows 4ty+i and 64+4ty+i, phys f4 = ks ^ (row&7)
            float4 zr[8];
#pragma unroll
            for (int i = 0; i < 4; ++i) {
                int r0 = 4 * ty + i;
                zr[i]     = *(const float4*)&zs[r0 * 32 + ((ks ^ (r0 & 7)) << 2)];
                zr[4 + i] = *(const float4*)&zs[(64 + r0) * 32 + ((ks ^ (r0 & 7)) << 2)];
            }
            // 8 e b128 straight from global (L1/L2), then 8 FMAs each
#pragma unroll
            for (int j = 0; j < 8; ++j) {
                const char* ep = (j < 4) ? eb0 : eb1;
                float4 ev = *(const float4*)(ep + kc * 128 + (j & 3) * 1024 + ks * 16);
#pragma unroll
                for (int i = 0; i < 8; ++i) {
                    acc[i][j] = __builtin_fmaf(zr[i].x, ev.x, acc[i][j]);
                    acc[i][j] = __builtin_fmaf(zr[i].y, ev.y, acc[i][j]);
                    acc[i][j] = __builtin_fmaf(zr[i].z, ev.z, acc[i][j]);
                    acc[i][j] = __builtin_fmaf(zr[i].w, ev.w, acc[i][j]);
                }
            }
        }
    }
    (void)rsw;

    // epilogue: token norms (bit-identical, from vq_anorm), distances, first-min
    float Aval[8];
    {
        float4 v0 = *(const float4*)(wsA + t0 + 4 * ty);
        float4 v1 = *(const float4*)(wsA + t0 + 64 + 4 * ty);
        Aval[0] = v0.x; Aval[1] = v0.y; Aval[2] = v0.z; Aval[3] = v0.w;
        Aval[4] = v1.x; Aval[5] = v1.y; Aval[6] = v1.z; Aval[7] = v1.w;
    }

    float best[8];
    int   bidx[8];
#pragma unroll
    for (int i = 0; i < 8; ++i) { best[i] = __builtin_inff(); bidx[i] = 0x7fffffff; }
#pragma unroll
    for (int i = 0; i < 8; ++i)
#pragma unroll
        for (int j = 0; j < 8; ++j) {
            int cl = (j < 4) ? (4 * tx + j) : (64 + 4 * tx + (j - 4));
            float t1 = Aval[i] + Bl[cl];
            float dist = t1 - 2.0f * acc[i][j];
            if (dist < best[i]) { best[i] = dist; bidx[i] = n0 + cl; }
        }

    // lexicographic (d, idx) min over the 16 tx-threads per token
#pragma unroll
    for (int i = 0; i < 8; ++i) {
        float d = best[i]; int w = bidx[i];
        for (int off = 8; off; off >>= 1) {
            float od = __shfl_xor(d, off);
            int   ow = __shfl_xor(w, off);
            if (od < d || (od == d && ow < w)) { d = od; w = ow; }
        }
        best[i] = d; bidx[i] = w;
    }

    // merge across code-tiles: key = d_bits<<32 | idx (d>0 so bits are monotone)
    if (tx == 0) {
#pragma unroll
        for (int i = 0; i < 8; ++i) {
            int tl = (i < 4) ? (4 * ty + i) : (64 + 4 * ty + (i - 4));
            unsigned long long key =
                ((unsigned long long)__float_as_uint(best[i]) << 32) |
                (unsigned int)bidx[i];
            atomicMin(&keys[t0 + tl], key);
        }
    }
}

// ---------------- kernel 2: gather z_q, indices, fp64 loss partials.
__global__ __launch_bounds__(256) void vq_gather(const float* __restrict__ z,
                                                 const float* __restrict__ cb,
                                                 const unsigned long long* __restrict__ keys,
                                                 double* __restrict__ loss_acc,
                                                 float* __restrict__ out)
{
    __shared__ double lred[4];
    const int tid = threadIdx.x;
    const int tx = tid & 15, ty = tid >> 4;
    const int t0 = blockIdx.x * 64;

    double ld = 0.0;
#pragma unroll
    for (int i = 0; i < 4; ++i) {
        int t = t0 + ty * 4 + i;
        unsigned long long key = keys[t];
        int w = (int)(unsigned int)(key & 0xFFFFFFFFull);
        const float4* crow = (const float4*)(cb + (size_t)w * DDIM);
        const float4* zrow = (const float4*)(z + (size_t)t * DDIM);
        float4* orow = (float4*)(out + (size_t)t * DDIM);
#pragma unroll
        for (int q = 0; q < 4; ++q) {
            int c4 = tx * 4 + q;
            float4 e4 = crow[c4];
            float4 z4 = zrow[c4];
            float4 o;
            float dx;
            dx = e4.x - z4.x; o.x = z4.x + dx; ld += (double)(dx * dx);
            dx = e4.y - z4.y; o.y = z4.y + dx; ld += (double)(dx * dx);
            dx = e4.z - z4.z; o.z = z4.z + dx; ld += (double)(dx * dx);
            dx = e4.w - z4.w; o.w = z4.w + dx; ld += (double)(dx * dx);
            orow[c4] = o;
        }
        if (tx == 0) out[IDX_OFF + t] = (float)w;
    }

    for (int off = 32; off; off >>= 1) ld += __shfl_down(ld, off);
    int lane = tid & 63, wvv = tid >> 6;
    if (lane == 0) lred[wvv] = ld;
    __syncthreads();
    if (tid == 0) {
        double s = (lred[0] + lred[1]) + (lred[2] + lred[3]);
        atomicAdd(loss_acc, s);
    }
}

// ---------------- kernel 3: finalize loss = fl(mf + fl(10*mf))
__global__ void vq_finish(const double* __restrict__ loss_acc, float* __restrict__ out)
{
#pragma clang fp contract(off)
    double m = *loss_acc / 16777216.0;
    float mf = (float)m;
    float second = 10.0f * mf;
    out[LOSS_OFF] = mf + second;
}

extern "C" void kernel_launch(void* const* d_in, const int* in_sizes, int n_in,
                              void* d_out, int out_size, void* d_ws, size_t ws_size,
                              hipStream_t stream)
{
    (void)in_sizes; (void)n_in; (void)out_size; (void)ws_size;
    const float* z  = (const float*)d_in[0];
    const float* cb = (const float*)d_in[1];
    float* out = (float*)d_out;
    double* loss_acc = (double*)d_ws;                                      // 8 B
    float* wsB = (float*)((char*)d_ws + 64);                               // 4 KB
    unsigned long long* keys = (unsigned long long*)((char*)d_ws + 8192);  // 512 KB
    float* wsA = (float*)((char*)d_ws + 532480);                           // 256 KB

    vq_prep<<<dim3(64), dim3(256), 0, stream>>>(cb, wsB, loss_acc, keys);
    vq_anorm<<<dim3(NTOK / 256), dim3(256), 0, stream>>>(z, wsA);
    vq_main<<<dim3(4096), dim3(256), 0, stream>>>(z, cb, wsB, wsA, keys);
    vq_gather<<<dim3(NTOK / 64), dim3(256), 0, stream>>>(z, cb, keys, loss_acc, out);
    vq_finish<<<dim3(1), dim3(1), 0, stream>>>(loss_acc, out);
}

// Round 16
// 474.114 us; speedup vs baseline: 2.0951x; 2.0951x over previous
//
#include <hip/hip_runtime.h>
#include <math.h>

// VQ quantizer: z [65536, 256] fp32, codebook [1024, 256] fp32.
// Outputs flat: z_q [16777216] | loss [1] | indices [65536] (as float values).
//
// Numerics contract (validated R1..R15, absmax 0.0 — keep bit-identical):
//   A_t = sum(z_t^2)  -- numpy pairwise order (8-acc chains, 128-blocks, fixed tree)
//   B_n = sum(e_n^2)  -- same
//   d   = fl( fl(A+B) - 2*M ),  M = fp32 fma-accumulated dot, k ascending
//   argmin: global first-min == lexicographic min of key (d_bits<<32 | idx)
//   z_q_out = fl( z + fl(e - z) ),  loss = fl(mf + fl(10*mf)), mf=(float)(Σdx²/2^24)
//
// R15 lesson: e direct-from-global = VMEM latency bound (VALU 42%). R16: BOTH
// tiles in LDS [row][32k] with swizzle s(row)=(row>>2)&7 so the read column
// ((row>>2)&7)^ks is per-thread CONSTANT across its 8 rows -> row offsets are
// compile-time ds_read immediates; per 4-k step: ~4 addr VALU + 16 b128 +
// 256 FMA (2% overhead; LDS pipe at 0.5x VALU). z cols broadcast 16-wide,
// e cols 8-distinct x 2-way: conflict-free.
// HARD RULE: never pass a 2nd __launch_bounds__ arg (VGPR=64 pin + GB spills).

#define NTOK     65536
#define DDIM     256
#define NCODE    1024
#define LOSS_OFF 16777216
#define IDX_OFF  16777217

// ws layout: [0] double loss_acc | [64] float wsB[1024] | [8192] u64 keys[65536]
//            | [532480] float wsA[65536]

#define GLOAD_LDS16(gp, lp)                                                       \
    __builtin_amdgcn_global_load_lds(                                             \
        (const __attribute__((address_space(1))) void*)(gp),                      \
        (__attribute__((address_space(3))) void*)(lp), 16, 0, 0)

// ---------------- kernel 0: B_n (numpy-pairwise), zero loss, init argmin keys.
__global__ void vq_prep(const float* __restrict__ cb, float* __restrict__ wsB,
                        double* __restrict__ loss_acc,
                        unsigned long long* __restrict__ keys)
{
#pragma clang fp contract(off)
    int gid = blockIdx.x * blockDim.x + threadIdx.x;
    if (gid == 0) *loss_acc = 0.0;
    unsigned long long* kp = keys + (size_t)gid * 4;
    kp[0] = kp[1] = kp[2] = kp[3] = 0xFFFFFFFFFFFFFFFFull;
    if (gid >= NCODE) return;
    const float* a = cb + gid * DDIM;
    float half[2];
    for (int h = 0; h < 2; ++h) {
        const float* b = a + h * 128;
        float r[8];
#pragma unroll
        for (int j = 0; j < 8; ++j) { float v = b[j]; r[j] = v * v; }
        for (int i = 8; i < 128; i += 8) {
#pragma unroll
            for (int j = 0; j < 8; ++j) { float v = b[i + j]; float s = v * v; r[j] = r[j] + s; }
        }
        half[h] = ((r[0] + r[1]) + (r[2] + r[3])) + ((r[4] + r[5]) + (r[6] + r[7]));
    }
    wsB[gid] = half[0] + half[1];
}

// ---------------- kernel 0b: A_t (numpy-pairwise) for every token.
__global__ void vq_anorm(const float* __restrict__ z, float* __restrict__ wsA)
{
#pragma clang fp contract(off)
    int t = blockIdx.x * blockDim.x + threadIdx.x;
    const float* a = z + (size_t)t * DDIM;
    float half[2];
    for (int h = 0; h < 2; ++h) {
        const float* b = a + h * 128;
        float r[8];
#pragma unroll
        for (int j = 0; j < 8; ++j) { float v = b[j]; r[j] = v * v; }
        for (int i = 8; i < 128; i += 8) {
#pragma unroll
            for (int j = 0; j < 8; ++j) { float v = b[i + j]; float s = v * v; r[j] = r[j] + s; }
        }
        half[h] = ((r[0] + r[1]) + (r[2] + r[3])) + ((r[4] + r[5]) + (r[6] + r[7]));
    }
    wsA[t] = half[0] + half[1];
}

// ---------------- kernel 1: distance GEMM + per-tile argmin -> atomicMin keys.
// Grid 4096 x 256: block b -> xcd = b&7, sl = b>>3, token-tile tt = xcd*64+(sl>>3),
// code-tile ct = sl&7 (siblings of a token-tile share one XCD's L2).
// Thread (tx,ty): tokens {4ty+i, 64+4ty+i} and codes {4tx+j, 64+4tx+j}, both
// from LDS [row][32k] tiles, f4-block kb stored at phys kb ^ ((row>>2)&7).
__global__ __launch_bounds__(256) void vq_main(const float* __restrict__ z,
                                               const float* __restrict__ cb,
                                               const float* __restrict__ wsB,
                                               const float* __restrict__ wsA,
                                               unsigned long long* __restrict__ keys)
{
    __shared__ float zs[128 * 32];   // 16 KB tokens
    __shared__ float es[128 * 32];   // 16 KB codes
    __shared__ float Bl[128];

    const int tid = threadIdx.x;
    const int tx = tid & 15, ty = tid >> 4;      // 16x16 thread grid
    const int b = blockIdx.x;
    const int xcd = b & 7, sl = b >> 3;
    const int tt = xcd * 64 + (sl >> 3);
    const int ct = sl & 7;
    const int t0 = tt * 128;
    const int n0 = ct * 128;

    if (tid < 128) Bl[tid] = wsB[n0 + tid];

    // staging: slot fr = tid+256s -> row fr>>3, phys f4 col fr&7; source col =
    // phys ^ ((row>>2)&7)  (both-sides swizzle, rule 21; linear gload_lds dest)
    const char* zc = (const char*)z;
    const char* ec = (const char*)cb;
    int zo[4], eo[4];
#pragma unroll
    for (int s = 0; s < 4; ++s) {
        int fr = tid + 256 * s;
        int row = fr >> 3;
        int csrc = (fr & 7) ^ ((row >> 2) & 7);
        zo[s] = (t0 + row) * 1024 + csrc * 16;
        eo[s] = (n0 + row) * 1024 + csrc * 16;
    }

    float acc[8][8];
#pragma unroll
    for (int i = 0; i < 8; ++i)
#pragma unroll
        for (int j = 0; j < 8; ++j) acc[i][j] = 0.0f;

    // per-thread LDS byte bases (row offsets are compile-time immediates)
    const char* zB = (const char*)zs + 4 * ty * 128;   // rows 4ty.., +8192 for +64
    const char* eB = (const char*)es + 4 * tx * 128;
    const int zsw = ty & 7;   // read col = (zsw ^ ks) << 4
    const int esw = tx & 7;

    for (int kc = 0; kc < 8; ++kc) {
        if (kc) __syncthreads();             // readers of kc-1 done
#pragma unroll
        for (int s = 0; s < 4; ++s) {
            GLOAD_LDS16(zc + (zo[s] + kc * 128), (char*)zs + (tid + 256 * s) * 16);
            GLOAD_LDS16(ec + (eo[s] + kc * 128), (char*)es + (tid + 256 * s) * 16);
        }
        __syncthreads();                     // vmcnt(0) drain + visibility

#pragma unroll
        for (int ks = 0; ks < 8; ++ks) {
            const int cz = ((zsw ^ ks) << 4);
            const int ce = ((esw ^ ks) << 4);
            const char* zp = zB + cz;
            const char* ep = eB + ce;
            float4 zr[8];
#pragma unroll
            for (int i = 0; i < 4; ++i) {
                zr[i]     = *(const float4*)(zp + i * 128);          // row 4ty+i
                zr[4 + i] = *(const float4*)(zp + 8192 + i * 128);   // row 64+4ty+i
            }
#pragma unroll
            for (int j = 0; j < 8; ++j) {
                float4 ev = (j < 4)
                    ? *(const float4*)(ep + j * 128)                 // code 4tx+j
                    : *(const float4*)(ep + 8192 + (j - 4) * 128);   // 64+4tx+(j-4)
#pragma unroll
                for (int i = 0; i < 8; ++i) {
                    acc[i][j] = __builtin_fmaf(zr[i].x, ev.x, acc[i][j]);
                    acc[i][j] = __builtin_fmaf(zr[i].y, ev.y, acc[i][j]);
                    acc[i][j] = __builtin_fmaf(zr[i].z, ev.z, acc[i][j]);
                    acc[i][j] = __builtin_fmaf(zr[i].w, ev.w, acc[i][j]);
                }
            }
        }
    }

    // epilogue: token norms (bit-identical, from vq_anorm), distances, first-min
    float Aval[8];
    {
        float4 v0 = *(const float4*)(wsA + t0 + 4 * ty);
        float4 v1 = *(const float4*)(wsA + t0 + 64 + 4 * ty);
        Aval[0] = v0.x; Aval[1] = v0.y; Aval[2] = v0.z; Aval[3] = v0.w;
        Aval[4] = v1.x; Aval[5] = v1.y; Aval[6] = v1.z; Aval[7] = v1.w;
    }

    float best[8];
    int   bidx[8];
#pragma unroll
    for (int i = 0; i < 8; ++i) { best[i] = __builtin_inff(); bidx[i] = 0x7fffffff; }
#pragma unroll
    for (int i = 0; i < 8; ++i)
#pragma unroll
        for (int j = 0; j < 8; ++j) {
            int cl = (j < 4) ? (4 * tx + j) : (64 + 4 * tx + (j - 4));
            float t1 = Aval[i] + Bl[cl];
            float dist = t1 - 2.0f * acc[i][j];
            if (dist < best[i]) { best[i] = dist; bidx[i] = n0 + cl; }
        }

    // lexicographic (d, idx) min over the 16 tx-threads per token
#pragma unroll
    for (int i = 0; i < 8; ++i) {
        float d = best[i]; int w = bidx[i];
        for (int off = 8; off; off >>= 1) {
            float od = __shfl_xor(d, off);
            int   ow = __shfl_xor(w, off);
            if (od < d || (od == d && ow < w)) { d = od; w = ow; }
        }
        best[i] = d; bidx[i] = w;
    }

    // merge across code-tiles: key = d_bits<<32 | idx (d>0 so bits are monotone)
    if (tx == 0) {
#pragma unroll
        for (int i = 0; i < 8; ++i) {
            int tl = (i < 4) ? (4 * ty + i) : (64 + 4 * ty + (i - 4));
            unsigned long long key =
                ((unsigned long long)__float_as_uint(best[i]) << 32) |
                (unsigned int)bidx[i];
            atomicMin(&keys[t0 + tl], key);
        }
    }
}

// ---------------- kernel 2: gather z_q, indices, fp64 loss partials.
__global__ __launch_bounds__(256) void vq_gather(const float* __restrict__ z,
                                                 const float* __restrict__ cb,
                                                 const unsigned long long* __restrict__ keys,
                                                 double* __restrict__ loss_acc,
                                                 float* __restrict__ out)
{
    __shared__ double lred[4];
    const int tid = threadIdx.x;
    const int tx = tid & 15, ty = tid >> 4;
    const int t0 = blockIdx.x * 64;

    double ld = 0.0;
#pragma unroll
    for (int i = 0; i < 4; ++i) {
        int t = t0 + ty * 4 + i;
        unsigned long long key = keys[t];
        int w = (int)(unsigned int)(key & 0xFFFFFFFFull);
        const float4* crow = (const float4*)(cb + (size_t)w * DDIM);
        const float4* zrow = (const float4*)(z + (size_t)t * DDIM);
        float4* orow = (float4*)(out + (size_t)t * DDIM);
#pragma unroll
        for (int q = 0; q < 4; ++q) {
            int c4 = tx * 4 + q;
            float4 e4 = crow[c4];
            float4 z4 = zrow[c4];
            float4 o;
            float dx;
            dx = e4.x - z4.x; o.x = z4.x + dx; ld += (double)(dx * dx);
            dx = e4.y - z4.y; o.y = z4.y + dx; ld += (double)(dx * dx);
            dx = e4.z - z4.z; o.z = z4.z + dx; ld += (double)(dx * dx);
            dx = e4.w - z4.w; o.w = z4.w + dx; ld += (double)(dx * dx);
            orow[c4] = o;
        }
        if (tx == 0) out[IDX_OFF + t] = (float)w;
    }

    for (int off = 32; off; off >>= 1) ld += __shfl_down(ld, off);
    int lane = tid & 63, wvv = tid >> 6;
    if (lane == 0) lred[wvv] = ld;
    __syncthreads();
    if (tid == 0) {
        double s = (lred[0] + lred[1]) + (lred[2] + lred[3]);
        atomicAdd(loss_acc, s);
    }
}

// ---------------- kernel 3: finalize loss = fl(mf + fl(10*mf))
__global__ void vq_finish(const double* __restrict__ loss_acc, float* __restrict__ out)
{
#pragma clang fp contract(off)
    double m = *loss_acc / 16777216.0;
    float mf = (float)m;
    float second = 10.0f * mf;
    out[LOSS_OFF] = mf + second;
}

extern "C" void kernel_launch(void* const* d_in, const int* in_sizes, int n_in,
                              void* d_out, int out_size, void* d_ws, size_t ws_size,
                              hipStream_t stream)
{
    (void)in_sizes; (void)n_in; (void)out_size; (void)ws_size;
    const float* z  = (const float*)d_in[0];
    const float* cb = (const float*)d_in[1];
    float* out = (float*)d_out;
    double* loss_acc = (double*)d_ws;                                      // 8 B
    float* wsB = (float*)((char*)d_ws + 64);                               // 4 KB
    unsigned long long* keys = (unsigned long long*)((char*)d_ws + 8192);  // 512 KB
    float* wsA = (float*)((char*)d_ws + 532480);                           // 256 KB

    vq_prep<<<dim3(64), dim3(256), 0, stream>>>(cb, wsB, loss_acc, keys);
    vq_anorm<<<dim3(NTOK / 256), dim3(256), 0, stream>>>(z, wsA);
    vq_main<<<dim3(4096), dim3(256), 0, stream>>>(z, cb, wsB, wsA, keys);
    vq_gather<<<dim3(NTOK / 64), dim3(256), 0, stream>>>(z, cb, keys, loss_acc, out);
    vq_finish<<<dim3(1), dim3(1), 0, stream>>>(loss_acc, out);
}